// Round 10
// baseline (190.875 us; speedup 1.0000x reference)
//
#include <hip/hip_runtime.h>
#include <hip/hip_bf16.h>
#include <math.h>
#include <stdint.h>

#define N_TOK 8192
#define D_IN  1024
#define D_H   128
#define SPLIT 8

typedef __bf16 bf16;
typedef __attribute__((ext_vector_type(4))) __bf16 bf16x4;
typedef __attribute__((ext_vector_type(8))) __bf16 bf16x8;
typedef __attribute__((ext_vector_type(4))) float floatx4;

#define MFMA16(a, b, c) __builtin_amdgcn_mfma_f32_16x16x32_bf16((a), (b), (c), 0, 0, 0)

// sqrt(128) * log2(e): softmax computed in exp2 domain (saves the ln2 mul in
// every __expf; combine_kernel uses exp2f to match).
#define QSCALE 16.322625246404958f

// defer-max threshold (exp2 domain): skip O/l rescale unless the running max
// grew by more than this; P is then bounded by 2^8=256, safe in fp32 accum
// and bf16 opart (combine math is exact for any stored m).
#define RESCALE_THR 8.0f

__device__ __forceinline__ uint32_t pack2(float a, float b) {
    union { bf16 h[2]; uint32_t u; } z;
    z.h[0] = (bf16)a; z.h[1] = (bf16)b; return z.u;
}

// V fragment order (A-frag of V^T == B-frag of V): [ntile][dt][lane][j]
__device__ __forceinline__ size_t vtf_idx(int n, int d) {
    return ((size_t)((n >> 6) * 8 + (d >> 4)) << 10)
         + (((n >> 3) & 7) << 7) + ((d & 15) << 3) + (n & 7);
}
// K fragment order (A-frag of K == B-frag of K^T): [ktile][kc][mt][lane][j]
__device__ __forceinline__ size_t khf_idx(int n, int d) {
    return ((size_t)(((n >> 6) * 4 + (d >> 5)) * 4 + ((n >> 4) & 3)) << 9)
         + (((d >> 3) & 3) << 7) + ((n & 15) << 3) + (d & 7);
}

#define X_OCT (N_TOK * D_IN / 8)
#define W_OCT (3 * D_H * D_IN / 8)

// ---------------------------------------------------------------------------
// Kernel 0: one-time fp32 -> split-bf16 conversion into MFMA fragment order.
// (R3-verified form.)
// ---------------------------------------------------------------------------
__global__ __launch_bounds__(256)
void convert_kernel(const float* __restrict__ x,
                    const float* __restrict__ Wq,
                    const float* __restrict__ Wk,
                    const float* __restrict__ Wv,
                    bf16* __restrict__ xhf, bf16* __restrict__ xlf,
                    bf16* __restrict__ whf, bf16* __restrict__ wlf)
{
    const int gid = blockIdx.x * 256 + threadIdx.x;
    const float* src;
    bf16 *dh, *dl;
    size_t doff;
    if (gid < X_OCT) {
        int lane = gid & 63, fc = gid >> 6;
        int kc = fc & 31, mt = fc >> 5;
        int n  = mt * 16 + (lane & 15);
        int k0 = kc * 32 + ((lane >> 4) << 3);
        src = x + (size_t)n * D_IN + k0;
        dh = xhf; dl = xlf; doff = (size_t)gid << 3;
    } else {
        int w = gid - X_OCT;
        int y = w >> 14, r = w & 16383;
        int lane = r & 63, fc = r >> 6;
        int kc = fc & 31, ct = fc >> 5;
        int col = ct * 16 + (lane & 15);
        int k0  = kc * 32 + ((lane >> 4) << 3);
        const float* W = (y == 0) ? Wq : (y == 1) ? Wk : Wv;
        src = W + (size_t)col * D_IN + k0;
        dh = whf; dl = wlf; doff = (size_t)w << 3;
    }
    float4 a = *(const float4*)src;
    float4 b = *(const float4*)(src + 4);
    float vv[8] = { a.x, a.y, a.z, a.w, b.x, b.y, b.z, b.w };
    bf16x8 h, l;
    #pragma unroll
    for (int j = 0; j < 8; ++j) {
        bf16 hh = (bf16)vv[j];
        h[j] = hh;
        l[j] = (bf16)(vv[j] - (float)hh);
    }
    *(bf16x8*)(dh + doff) = h;
    *(bf16x8*)(dl + doff) = l;
}

// ---------------------------------------------------------------------------
// Kernel 1: QKV projection GEMM, split-bf16 3-pass MFMA.
// R3-VERIFIED FORM exactly.
// ---------------------------------------------------------------------------
__global__ __launch_bounds__(256)
void qkv_kernel(const bf16* __restrict__ xhf, const bf16* __restrict__ xlf,
                const bf16* __restrict__ whf, const bf16* __restrict__ wlf,
                bf16* __restrict__ q_hi, bf16* __restrict__ q_lo,
                bf16* __restrict__ khf, bf16* __restrict__ klf,
                bf16* __restrict__ vtf)
{
    __shared__ bf16 w_s[2][16384];   // [buf][(hl*16 + ct*2 + kci)*512 + idx]

    const int t    = threadIdx.x;
    const int lane = t & 63;
    const int wid  = t >> 6;
    const int wr   = wid >> 1;
    const int wc   = wid & 1;
    const int lid  = lane & 15;
    const int quad = lane >> 4;
    const int m0   = blockIdx.x * 64;
    const bf16* wh = whf + ((size_t)blockIdx.y << 17);
    const bf16* wl = wlf + ((size_t)blockIdx.y << 17);

    auto stage = [&](int c0, int buf) {
        #pragma unroll
        for (int i = 0; i < 8; ++i) {
            int p   = wid * 8 + i;            // 0..31
            int hl  = p >> 4, ct = (p >> 1) & 7, kci = p & 1;
            const bf16* src = (hl ? wl : wh)
                            + ((size_t)(ct * 32 + c0 + kci) << 9) + (lane << 3);
            bf16* dst = &w_s[buf][p << 9];
            __builtin_amdgcn_global_load_lds(
                (const __attribute__((address_space(1))) void*)src,
                (__attribute__((address_space(3))) void*)dst, 16, 0, 0);
        }
    };

    floatx4 acc[2][4];
    #pragma unroll
    for (int m = 0; m < 2; ++m)
        #pragma unroll
        for (int ct = 0; ct < 4; ++ct)
            #pragma unroll
            for (int r = 0; r < 4; ++r) acc[m][ct][r] = 0.f;

    stage(0, 0);

    for (int c = 0; c < 16; ++c) {
        const int c0 = c * 2;
        const int cb = c & 1;
        __syncthreads();
        if (c < 15) stage(c0 + 2, cb ^ 1);

        #pragma unroll
        for (int kci = 0; kci < 2; ++kci) {
            bf16x8 ah[2], al[2];
            #pragma unroll
            for (int m = 0; m < 2; ++m) {
                int mt = (m0 >> 4) + wr * 2 + m;
                const size_t xb = ((size_t)(mt * 32 + c0 + kci) << 9) + (lane << 3);
                ah[m] = *(const bf16x8*)(xhf + xb);
                al[m] = *(const bf16x8*)(xlf + xb);
            }
            #pragma unroll
            for (int ct = 0; ct < 4; ++ct) {
                const int pb = (((wc * 4 + ct) * 2 + kci) << 9) + (lane << 3);
                bf16x8 bh = *(const bf16x8*)&w_s[cb][pb];
                bf16x8 bl = *(const bf16x8*)&w_s[cb][(16 << 9) + pb];
                #pragma unroll
                for (int m = 0; m < 2; ++m) {
                    acc[m][ct] = MFMA16(ah[m], bh, acc[m][ct]);
                    acc[m][ct] = MFMA16(al[m], bh, acc[m][ct]);
                    acc[m][ct] = MFMA16(ah[m], bl, acc[m][ct]);
                }
            }
        }
    }

    if (blockIdx.y == 0) {
        #pragma unroll
        for (int s2 = 0; s2 < 2; ++s2)
            #pragma unroll
            for (int ct = 0; ct < 4; ++ct)
                #pragma unroll
                for (int r = 0; r < 4; ++r) {
                    int row = m0 + wr * 32 + s2 * 16 + quad * 4 + r;
                    int col = wc * 64 + ct * 16 + lid;
                    float a = acc[s2][ct][r] * QSCALE;
                    bf16 h = (bf16)a;
                    q_hi[(size_t)row * D_H + col] = h;
                    q_lo[(size_t)row * D_H + col] = (bf16)(a - (float)h);
                }
    } else if (blockIdx.y == 1) {
        #pragma unroll
        for (int s2 = 0; s2 < 2; ++s2)
            #pragma unroll
            for (int ct = 0; ct < 4; ++ct)
                #pragma unroll
                for (int r = 0; r < 4; ++r) {
                    int n = m0 + wr * 32 + s2 * 16 + quad * 4 + r;
                    int d = wc * 64 + ct * 16 + lid;
                    float a = acc[s2][ct][r];
                    bf16 h = (bf16)a;
                    size_t idx = khf_idx(n, d);
                    khf[idx] = h;
                    klf[idx] = (bf16)(a - (float)h);
                }
    } else {
        #pragma unroll
        for (int s2 = 0; s2 < 2; ++s2)
            #pragma unroll
            for (int ct = 0; ct < 4; ++ct)
                #pragma unroll
                for (int r = 0; r < 4; ++r) {
                    int n = m0 + wr * 32 + s2 * 16 + quad * 4 + r;
                    int d = wc * 64 + ct * 16 + lid;
                    vtf[vtf_idx(n, d)] = (bf16)acc[s2][ct][r];
                }
    }
}

// ---------------------------------------------------------------------------
// Kernel 2: flash attention, TRANSPOSED formulation (R9 base = best so far).
// ROUND-10 CHANGE (single, zero-register): PV reorder to cover vf1's L2
// latency. vf1's 8 loads issued after the pB build previously had only
// ~50 cyc of cover before their first consumer (the 2nd MFMA of the dt=0
// pair). Now: all 16 vf0-MFMAs run first (dt-major), then the l-MFMAs,
// then all 16 vf1-MFMAs — ~90-170 cyc of MFMA cover for vf1[0].
// o_acc dependency chains are unaffected (each o_acc[dt] still sees
// vf0-MFMA before vf1-MFMA). Keeps R9's kh kc-level double buffer,
// setprio, defer-max THR=8, balanced max tree.
// ---------------------------------------------------------------------------
#define BQ   128
#define BKEY 64

__global__ __launch_bounds__(256, 2)
void flash_kernel(const bf16* __restrict__ qh, const bf16* __restrict__ ql,
                  const bf16* __restrict__ khf, const bf16* __restrict__ klf,
                  const bf16* __restrict__ vtf,
                  bf16*  __restrict__ opart,   // [SPLIT][N][D_H] unnormalized
                  float* __restrict__ mpart,   // [SPLIT][N] (exp2 domain)
                  float* __restrict__ lpart)   // [SPLIT][N]
{
    __shared__ bf16 k_s[2][16384];   // [buf][ kh: 0..8191 | kl: 8192..16383 ]

    const int t     = threadIdx.x;
    const int lane  = t & 63;
    const int wid   = t >> 6;
    const int lid   = lane & 15;
    const int quad  = lane >> 4;
    const int q0    = blockIdx.x * BQ;
    const int strip = wid * 32;               // 32 q-rows per wave
    const int sp    = blockIdx.y;
    const int tile0 = sp * (N_TOK / BKEY / SPLIT);
    const int tile1 = tile0 + (N_TOK / BKEY / SPLIT);

    // Q as B-operand of Q^T: resident for the whole kernel.
    bf16x8 b_hi[2][4], b_lo[2][4];            // [ct: qrow-tile][kc]
    #pragma unroll
    for (int ct = 0; ct < 2; ++ct) {
        const size_t rowb = (size_t)(q0 + strip + ct * 16 + lid) * D_H + quad * 8;
        #pragma unroll
        for (int kc = 0; kc < 4; ++kc) {
            b_hi[ct][kc] = *(const bf16x8*)(qh + rowb + kc * 32);
            b_lo[ct][kc] = *(const bf16x8*)(ql + rowb + kc * 32);
        }
    }

    bf16x8 vones;
    #pragma unroll
    for (int j = 0; j < 8; ++j) vones[j] = (bf16)1.0f;

    float m_run[2] = { -INFINITY, -INFINITY };   // per qrow-tile ct
    floatx4 l_acc[2];
    #pragma unroll
    for (int ct = 0; ct < 2; ++ct)
        #pragma unroll
        for (int r = 0; r < 4; ++r) l_acc[ct][r] = 0.f;
    floatx4 o_acc[8][2];                          // [dt][ct] = O^T frags
    #pragma unroll
    for (int dt = 0; dt < 8; ++dt)
        #pragma unroll
        for (int ct = 0; ct < 2; ++ct)
            #pragma unroll
            for (int r = 0; r < 4; ++r) o_acc[dt][ct][r] = 0.f;

    auto stage = [&](int tile, int buf) {
        const bf16* gh = khf + ((size_t)tile << 13) + (wid << 11) + (lane << 3);
        const bf16* gl = klf + ((size_t)tile << 13) + (wid << 11) + (lane << 3);
        bf16* lh = &k_s[buf][wid << 11];
        bf16* ll = lh + 8192;
        #pragma unroll
        for (int i = 0; i < 4; ++i) {
            __builtin_amdgcn_global_load_lds(
                (const __attribute__((address_space(1))) void*)(gh + i * 512),
                (__attribute__((address_space(3))) void*)(lh + i * 512), 16, 0, 0);
            __builtin_amdgcn_global_load_lds(
                (const __attribute__((address_space(1))) void*)(gl + i * 512),
                (__attribute__((address_space(3))) void*)(ll + i * 512), 16, 0, 0);
        }
    };

    stage(tile0, 0);

    for (int tt = tile0; tt < tile1; ++tt) {
        const int cb = (tt - tile0) & 1;
        __syncthreads();                      // buf cb staged; other buf free
        if (tt + 1 < tile1) stage(tt + 1, cb ^ 1);   // overlaps whole tile

        // ---- S^T = K . Q^T : split-bf16 3-pass, 96 MFMA ----
        const bf16* khp = &k_s[cb][0];
        const bf16* klp = &k_s[cb][8192];
        floatx4 s[4][2];                       // [mt: key-tile][ct: qrow-tile]
        #pragma unroll
        for (int mt = 0; mt < 4; ++mt)
            #pragma unroll
            for (int ct = 0; ct < 2; ++ct)
                #pragma unroll
                for (int r = 0; r < 4; ++r) s[mt][ct][r] = 0.f;

        // K-hi kc-level double buffer: prefetch kc+1 under kc's MFMAs.
        bf16x8 kh[2][4];                       // [kc&1][mt]
        #pragma unroll
        for (int mt = 0; mt < 4; ++mt)
            kh[0][mt] = *(const bf16x8*)&khp[(mt << 9) + (lane << 3)];

        __builtin_amdgcn_s_setprio(1);
        #pragma unroll
        for (int kc = 0; kc < 4; ++kc) {
            const int cur = kc & 1;
            if (kc < 3) {
                #pragma unroll
                for (int mt = 0; mt < 4; ++mt)
                    kh[cur ^ 1][mt] = *(const bf16x8*)
                        &khp[(((kc + 1) * 4 + mt) << 9) + (lane << 3)];
            }
            #pragma unroll
            for (int mt = 0; mt < 4; ++mt) {
                const int fo = ((kc * 4 + mt) << 9) + (lane << 3);
                bf16x8 al = *(const bf16x8*)&klp[fo];
                #pragma unroll
                for (int ct = 0; ct < 2; ++ct) {
                    s[mt][ct] = MFMA16(kh[cur][mt], b_hi[ct][kc], s[mt][ct]);
                    s[mt][ct] = MFMA16(al,          b_hi[ct][kc], s[mt][ct]);
                    s[mt][ct] = MFMA16(kh[cur][mt], b_lo[ct][kc], s[mt][ct]);
                }
            }
        }
        __builtin_amdgcn_s_setprio(0);

        // ---- prefetch V kc2=0 A-frags (consumed after softmax) ----
        const bf16* vb = vtf + ((size_t)tt << 13) + (lane << 3);
        bf16x8 vf0[8];
        #pragma unroll
        for (int dt = 0; dt < 8; ++dt)
            vf0[dt] = *(const bf16x8*)(vb + ((size_t)dt << 10));

        // ---- softmax (exp2 domain): balanced max tree + 2 shfl ----
        float mx[2];
        #pragma unroll
        for (int ct = 0; ct < 2; ++ct) {
            float a0 = fmaxf(s[0][ct][0], s[0][ct][1]);
            float a1 = fmaxf(s[0][ct][2], s[0][ct][3]);
            float a2 = fmaxf(s[1][ct][0], s[1][ct][1]);
            float a3 = fmaxf(s[1][ct][2], s[1][ct][3]);
            float a4 = fmaxf(s[2][ct][0], s[2][ct][1]);
            float a5 = fmaxf(s[2][ct][2], s[2][ct][3]);
            float a6 = fmaxf(s[3][ct][0], s[3][ct][1]);
            float a7 = fmaxf(s[3][ct][2], s[3][ct][3]);
            float b0 = fmaxf(fmaxf(a0, a1), fmaxf(a2, a3));
            float b1 = fmaxf(fmaxf(a4, a5), fmaxf(a6, a7));
            float c0 = fmaxf(b0, b1);
            c0 = fmaxf(c0, __shfl_xor(c0, 16, 64));
            c0 = fmaxf(c0, __shfl_xor(c0, 32, 64));
            mx[ct] = c0;
        }

        // defer-max: move the running max (and rescale) only when it grew
        // by more than RESCALE_THR; otherwise P <= 2^THR, safe in fp32.
        const bool need = __any((mx[0] - m_run[0] > RESCALE_THR) ||
                                (mx[1] - m_run[1] > RESCALE_THR));
        float alpha[2] = { 1.f, 1.f };
        if (need) {
            #pragma unroll
            for (int ct = 0; ct < 2; ++ct) {
                float mn = fmaxf(m_run[ct], mx[ct]);
                alpha[ct] = exp2f(m_run[ct] - mn);
                m_run[ct] = mn;
            }
        }

        uint32_t u0[4][2], u1[4][2];
        #pragma unroll
        for (int ct = 0; ct < 2; ++ct)
            #pragma unroll
            for (int mt = 0; mt < 4; ++mt) {
                float p0 = exp2f(s[mt][ct][0] - m_run[ct]);
                float p1 = exp2f(s[mt][ct][1] - m_run[ct]);
                float p2 = exp2f(s[mt][ct][2] - m_run[ct]);
                float p3 = exp2f(s[mt][ct][3] - m_run[ct]);
                u0[mt][ct] = pack2(p0, p1);
                u1[mt][ct] = pack2(p2, p3);
            }

        // ---- build P^T B-frags in-register (lane permutation) ----
        // target lane (quad,lid), frag (kc2,ct), j=0..7 needs
        // P^T[key=kc2*32+quad*8+j][qrow=ct*16+lid]; source element lives in
        // lane (2*(quad&1) + (j>>2))*16+lid, s[kc2*2+(quad>>1)][ct] reg j&3.
        bf16x8 pB[2][2];
        {
            const int lsrc = ((quad & 1) << 5) + lid;
            const bool himt = (quad & 2) != 0;
            #pragma unroll
            for (int kc2 = 0; kc2 < 2; ++kc2)
                #pragma unroll
                for (int ct = 0; ct < 2; ++ct) {
                    const int mA = kc2 * 2, mB = kc2 * 2 + 1;
                    uint32_t w0a = __shfl((int)u0[mA][ct], lsrc, 64);
                    uint32_t w0b = __shfl((int)u0[mB][ct], lsrc, 64);
                    uint32_t w1a = __shfl((int)u1[mA][ct], lsrc, 64);
                    uint32_t w1b = __shfl((int)u1[mB][ct], lsrc, 64);
                    uint32_t w2a = __shfl((int)u0[mA][ct], lsrc + 16, 64);
                    uint32_t w2b = __shfl((int)u0[mB][ct], lsrc + 16, 64);
                    uint32_t w3a = __shfl((int)u1[mA][ct], lsrc + 16, 64);
                    uint32_t w3b = __shfl((int)u1[mB][ct], lsrc + 16, 64);
                    union { uint32_t w[4]; bf16x8 v; } z;
                    z.w[0] = himt ? w0b : w0a;
                    z.w[1] = himt ? w1b : w1a;
                    z.w[2] = himt ? w2b : w2a;
                    z.w[3] = himt ? w3b : w3a;
                    pB[kc2][ct] = z.v;
                }
        }

        // ---- prefetch V kc2=1 (covered by the vf0 MFMA pass below) ----
        bf16x8 vf1[8];
        #pragma unroll
        for (int dt = 0; dt < 8; ++dt)
            vf1[dt] = *(const bf16x8*)(vb + ((size_t)dt << 10) + 512);

        // ---- rescale (only when the running max actually moved >THR) ----
        if (need) {
            #pragma unroll
            for (int ct = 0; ct < 2; ++ct) {
                #pragma unroll
                for (int r = 0; r < 4; ++r) l_acc[ct][r] *= alpha[ct];
                #pragma unroll
                for (int dt = 0; dt < 8; ++dt)
                    #pragma unroll
                    for (int r = 0; r < 4; ++r)
                        o_acc[dt][ct][r] *= alpha[ct];
            }
        }

        // ---- O^T += V^T P^T ; l += ones.P^T ----
        // vf0 pass first (data ready since before softmax), then l, then the
        // vf1 pass — vf1's L2 loads get ~18 MFMAs of cover before first use.
        __builtin_amdgcn_s_setprio(1);
        #pragma unroll
        for (int dt = 0; dt < 8; ++dt)
            #pragma unroll
            for (int ct = 0; ct < 2; ++ct)
                o_acc[dt][ct] = MFMA16(vf0[dt], pB[0][ct], o_acc[dt][ct]);
        #pragma unroll
        for (int ct = 0; ct < 2; ++ct) {
            l_acc[ct] = MFMA16(vones, pB[0][ct], l_acc[ct]);
            l_acc[ct] = MFMA16(vones, pB[1][ct], l_acc[ct]);
        }
        #pragma unroll
        for (int dt = 0; dt < 8; ++dt)
            #pragma unroll
            for (int ct = 0; ct < 2; ++ct)
                o_acc[dt][ct] = MFMA16(vf1[dt], pB[1][ct], o_acc[dt][ct]);
        __builtin_amdgcn_s_setprio(0);
    }

    // ---- epilogue: O^T regs -> opart[qrow][d] (packed u32 stores) ----
    uint32_t* opw = (uint32_t*)(opart + (size_t)sp * N_TOK * D_H);
    #pragma unroll
    for (int dt = 0; dt < 8; ++dt)
        #pragma unroll
        for (int ct = 0; ct < 2; ++ct) {
            int qrow  = q0 + strip + ct * 16 + lid;
            int dbase = dt * 16 + quad * 4;
            opw[(qrow * D_H + dbase) >> 1]     = pack2(o_acc[dt][ct][0], o_acc[dt][ct][1]);
            opw[(qrow * D_H + dbase + 2) >> 1] = pack2(o_acc[dt][ct][2], o_acc[dt][ct][3]);
        }
    if (quad == 0) {
        #pragma unroll
        for (int ct = 0; ct < 2; ++ct) {
            int row = q0 + strip + ct * 16 + lid;
            mpart[(size_t)sp * N_TOK + row] = m_run[ct];
            lpart[(size_t)sp * N_TOK + row] = l_acc[ct][0];
        }
    }
}

// ---------------------------------------------------------------------------
// Kernel 3: merge the SPLIT partials (exp2 domain).
// ---------------------------------------------------------------------------
__global__ __launch_bounds__(256)
void combine_kernel(const bf16* __restrict__ opart,
                    const float* __restrict__ mpart,
                    const float* __restrict__ lpart,
                    float* __restrict__ out)
{
    const int t   = threadIdx.x;
    const int row = blockIdx.x * 16 + (t >> 4);
    const int c0  = (t & 15) * 8;

    float ms[SPLIT], ls[SPLIT];
    float mstar = -INFINITY;
    #pragma unroll
    for (int s = 0; s < SPLIT; ++s) {
        ms[s] = mpart[(size_t)s * N_TOK + row];
        ls[s] = lpart[(size_t)s * N_TOK + row];
        mstar = fmaxf(mstar, ms[s]);
    }
    float acc[8] = {};
    float L = 0.f;
    #pragma unroll
    for (int s = 0; s < SPLIT; ++s) {
        float w = exp2f(ms[s] - mstar);
        L += w * ls[s];
        bf16x8 o = *(const bf16x8*)&opart[((size_t)s * N_TOK + row) * D_H + c0];
        #pragma unroll
        for (int j = 0; j < 8; ++j)
            acc[j] += w * (float)o[j];
    }
    float inv = 1.f / L;
    float* dst = &out[(size_t)row * D_H + c0];
    *(float4*)(dst + 0) = make_float4(acc[0] * inv, acc[1] * inv,
                                      acc[2] * inv, acc[3] * inv);
    *(float4*)(dst + 4) = make_float4(acc[4] * inv, acc[5] * inv,
                                      acc[6] * inv, acc[7] * inv);
}

// ---------------------------------------------------------------------------
extern "C" void kernel_launch(void* const* d_in, const int* in_sizes, int n_in,
                              void* d_out, int out_size, void* d_ws, size_t ws_size,
                              hipStream_t stream) {
    const float* x  = (const float*)d_in[0];
    const float* Wq = (const float*)d_in[1];
    const float* Wk = (const float*)d_in[2];
    const float* Wv = (const float*)d_in[3];
    float* out = (float*)d_out;

    bf16* wsb = (bf16*)d_ws;
    const size_t SZ = (size_t)N_TOK * D_H;
    bf16* xhf = wsb;
    bf16* xlf = xhf + (size_t)X_OCT * 8;
    bf16* whf = xlf + (size_t)X_OCT * 8;
    bf16* wlf = whf + (size_t)W_OCT * 8;
    bf16* qh  = wlf + (size_t)W_OCT * 8;
    bf16* ql  = qh + SZ;
    bf16* khf = ql + SZ;
    bf16* klf = khf + SZ;
    bf16* vtf = klf + SZ;
    bf16* opart = vtf + SZ;
    float* mpart = (float*)(opart + (size_t)SPLIT * SZ);
    float* lpart = mpart + (size_t)SPLIT * N_TOK;

    convert_kernel<<<dim3((X_OCT + W_OCT) / 256), 256, 0, stream>>>(
        x, Wq, Wk, Wv, xhf, xlf, whf, wlf);
    qkv_kernel<<<dim3(N_TOK / 64, 3), 256, 0, stream>>>(
        xhf, xlf, whf, wlf, qh, ql, khf, klf, vtf);
    flash_kernel<<<dim3(N_TOK / BQ, SPLIT), 256, 0, stream>>>(
        qh, ql, khf, klf, vtf, opart, mpart, lpart);
    combine_kernel<<<dim3(N_TOK / 16), 256, 0, stream>>>(opart, mpart, lpart, out);
}

// Round 12
// 189.157 us; speedup vs baseline: 1.0091x; 1.0091x over previous
//
#include <hip/hip_runtime.h>
#include <hip/hip_bf16.h>
#include <math.h>
#include <stdint.h>

#define N_TOK 8192
#define D_IN  1024
#define D_H   128
#define SPLIT 8

typedef __bf16 bf16;
typedef __attribute__((ext_vector_type(4))) __bf16 bf16x4;
typedef __attribute__((ext_vector_type(8))) __bf16 bf16x8;
typedef __attribute__((ext_vector_type(4))) float floatx4;

#define MFMA16(a, b, c) __builtin_amdgcn_mfma_f32_16x16x32_bf16((a), (b), (c), 0, 0, 0)

// sqrt(128) * log2(e): softmax computed in exp2 domain (saves the ln2 mul in
// every __expf; combine_kernel uses exp2f to match).
#define QSCALE 16.322625246404958f

// defer-max threshold (exp2 domain): skip O/l rescale unless the running max
// grew by more than this; P is then bounded by 2^8=256, safe in fp32 accum
// and bf16 opart (combine math is exact for any stored m).
#define RESCALE_THR 8.0f

__device__ __forceinline__ uint32_t pack2(float a, float b) {
    union { bf16 h[2]; uint32_t u; } z;
    z.h[0] = (bf16)a; z.h[1] = (bf16)b; return z.u;
}

// V fragment order (A-frag of V^T == B-frag of V): [ntile][dt][lane][j]
__device__ __forceinline__ size_t vtf_idx(int n, int d) {
    return ((size_t)((n >> 6) * 8 + (d >> 4)) << 10)
         + (((n >> 3) & 7) << 7) + ((d & 15) << 3) + (n & 7);
}
// K fragment order (A-frag of K == B-frag of K^T): [ktile][kc][mt][lane][j]
__device__ __forceinline__ size_t khf_idx(int n, int d) {
    return ((size_t)(((n >> 6) * 4 + (d >> 5)) * 4 + ((n >> 4) & 3)) << 9)
         + (((d >> 3) & 3) << 7) + ((n & 15) << 3) + (d & 7);
}

#define X_OCT (N_TOK * D_IN / 8)
#define W_OCT (3 * D_H * D_IN / 8)

// ---------------------------------------------------------------------------
// Kernel 0: one-time fp32 -> split-bf16 conversion into MFMA fragment order.
// (R3-verified form.)
// ---------------------------------------------------------------------------
__global__ __launch_bounds__(256)
void convert_kernel(const float* __restrict__ x,
                    const float* __restrict__ Wq,
                    const float* __restrict__ Wk,
                    const float* __restrict__ Wv,
                    bf16* __restrict__ xhf, bf16* __restrict__ xlf,
                    bf16* __restrict__ whf, bf16* __restrict__ wlf)
{
    const int gid = blockIdx.x * 256 + threadIdx.x;
    const float* src;
    bf16 *dh, *dl;
    size_t doff;
    if (gid < X_OCT) {
        int lane = gid & 63, fc = gid >> 6;
        int kc = fc & 31, mt = fc >> 5;
        int n  = mt * 16 + (lane & 15);
        int k0 = kc * 32 + ((lane >> 4) << 3);
        src = x + (size_t)n * D_IN + k0;
        dh = xhf; dl = xlf; doff = (size_t)gid << 3;
    } else {
        int w = gid - X_OCT;
        int y = w >> 14, r = w & 16383;
        int lane = r & 63, fc = r >> 6;
        int kc = fc & 31, ct = fc >> 5;
        int col = ct * 16 + (lane & 15);
        int k0  = kc * 32 + ((lane >> 4) << 3);
        const float* W = (y == 0) ? Wq : (y == 1) ? Wk : Wv;
        src = W + (size_t)col * D_IN + k0;
        dh = whf; dl = wlf; doff = (size_t)w << 3;
    }
    float4 a = *(const float4*)src;
    float4 b = *(const float4*)(src + 4);
    float vv[8] = { a.x, a.y, a.z, a.w, b.x, b.y, b.z, b.w };
    bf16x8 h, l;
    #pragma unroll
    for (int j = 0; j < 8; ++j) {
        bf16 hh = (bf16)vv[j];
        h[j] = hh;
        l[j] = (bf16)(vv[j] - (float)hh);
    }
    *(bf16x8*)(dh + doff) = h;
    *(bf16x8*)(dl + doff) = l;
}

// ---------------------------------------------------------------------------
// Kernel 1: QKV projection GEMM, split-bf16 3-pass MFMA.
// R3-VERIFIED FORM exactly.
// ---------------------------------------------------------------------------
__global__ __launch_bounds__(256)
void qkv_kernel(const bf16* __restrict__ xhf, const bf16* __restrict__ xlf,
                const bf16* __restrict__ whf, const bf16* __restrict__ wlf,
                bf16* __restrict__ q_hi, bf16* __restrict__ q_lo,
                bf16* __restrict__ khf, bf16* __restrict__ klf,
                bf16* __restrict__ vtf)
{
    __shared__ bf16 w_s[2][16384];   // [buf][(hl*16 + ct*2 + kci)*512 + idx]

    const int t    = threadIdx.x;
    const int lane = t & 63;
    const int wid  = t >> 6;
    const int wr   = wid >> 1;
    const int wc   = wid & 1;
    const int lid  = lane & 15;
    const int quad = lane >> 4;
    const int m0   = blockIdx.x * 64;
    const bf16* wh = whf + ((size_t)blockIdx.y << 17);
    const bf16* wl = wlf + ((size_t)blockIdx.y << 17);

    auto stage = [&](int c0, int buf) {
        #pragma unroll
        for (int i = 0; i < 8; ++i) {
            int p   = wid * 8 + i;            // 0..31
            int hl  = p >> 4, ct = (p >> 1) & 7, kci = p & 1;
            const bf16* src = (hl ? wl : wh)
                            + ((size_t)(ct * 32 + c0 + kci) << 9) + (lane << 3);
            bf16* dst = &w_s[buf][p << 9];
            __builtin_amdgcn_global_load_lds(
                (const __attribute__((address_space(1))) void*)src,
                (__attribute__((address_space(3))) void*)dst, 16, 0, 0);
        }
    };

    floatx4 acc[2][4];
    #pragma unroll
    for (int m = 0; m < 2; ++m)
        #pragma unroll
        for (int ct = 0; ct < 4; ++ct)
            #pragma unroll
            for (int r = 0; r < 4; ++r) acc[m][ct][r] = 0.f;

    stage(0, 0);

    for (int c = 0; c < 16; ++c) {
        const int c0 = c * 2;
        const int cb = c & 1;
        __syncthreads();
        if (c < 15) stage(c0 + 2, cb ^ 1);

        #pragma unroll
        for (int kci = 0; kci < 2; ++kci) {
            bf16x8 ah[2], al[2];
            #pragma unroll
            for (int m = 0; m < 2; ++m) {
                int mt = (m0 >> 4) + wr * 2 + m;
                const size_t xb = ((size_t)(mt * 32 + c0 + kci) << 9) + (lane << 3);
                ah[m] = *(const bf16x8*)(xhf + xb);
                al[m] = *(const bf16x8*)(xlf + xb);
            }
            #pragma unroll
            for (int ct = 0; ct < 4; ++ct) {
                const int pb = (((wc * 4 + ct) * 2 + kci) << 9) + (lane << 3);
                bf16x8 bh = *(const bf16x8*)&w_s[cb][pb];
                bf16x8 bl = *(const bf16x8*)&w_s[cb][(16 << 9) + pb];
                #pragma unroll
                for (int m = 0; m < 2; ++m) {
                    acc[m][ct] = MFMA16(ah[m], bh, acc[m][ct]);
                    acc[m][ct] = MFMA16(al[m], bh, acc[m][ct]);
                    acc[m][ct] = MFMA16(ah[m], bl, acc[m][ct]);
                }
            }
        }
    }

    if (blockIdx.y == 0) {
        #pragma unroll
        for (int s2 = 0; s2 < 2; ++s2)
            #pragma unroll
            for (int ct = 0; ct < 4; ++ct)
                #pragma unroll
                for (int r = 0; r < 4; ++r) {
                    int row = m0 + wr * 32 + s2 * 16 + quad * 4 + r;
                    int col = wc * 64 + ct * 16 + lid;
                    float a = acc[s2][ct][r] * QSCALE;
                    bf16 h = (bf16)a;
                    q_hi[(size_t)row * D_H + col] = h;
                    q_lo[(size_t)row * D_H + col] = (bf16)(a - (float)h);
                }
    } else if (blockIdx.y == 1) {
        #pragma unroll
        for (int s2 = 0; s2 < 2; ++s2)
            #pragma unroll
            for (int ct = 0; ct < 4; ++ct)
                #pragma unroll
                for (int r = 0; r < 4; ++r) {
                    int n = m0 + wr * 32 + s2 * 16 + quad * 4 + r;
                    int d = wc * 64 + ct * 16 + lid;
                    float a = acc[s2][ct][r];
                    bf16 h = (bf16)a;
                    size_t idx = khf_idx(n, d);
                    khf[idx] = h;
                    klf[idx] = (bf16)(a - (float)h);
                }
    } else {
        #pragma unroll
        for (int s2 = 0; s2 < 2; ++s2)
            #pragma unroll
            for (int ct = 0; ct < 4; ++ct)
                #pragma unroll
                for (int r = 0; r < 4; ++r) {
                    int n = m0 + wr * 32 + s2 * 16 + quad * 4 + r;
                    int d = wc * 64 + ct * 16 + lid;
                    vtf[vtf_idx(n, d)] = (bf16)acc[s2][ct][r];
                }
    }
}

// ---------------------------------------------------------------------------
// Kernel 2: flash attention, TRANSPOSED formulation — R9-VERIFIED EXACTLY
// (best measured: flash 88.4 us, total 189.9 us; R11 bench was an infra
// failure on identical code). Structure: S^T = K.Q^T (A=K frags from LDS,
// B=Q frags resident), O^T = V^T.P^T (A=V frags from global, B=P^T built
// in-register via lane shuffles). K double-buffered in LDS via
// global_load_lds; kh kc-level register double-buffer; setprio around MFMA
// clusters; defer-max THR=8; balanced max tree. Per-wave state floor ~230
// unified regs -> 2 waves/SIMD forced (R5: min-4 spills 800 MB);
// launch_bounds(256,2), grid (64,8) = 2 blocks/CU.
// ---------------------------------------------------------------------------
#define BQ   128
#define BKEY 64

__global__ __launch_bounds__(256, 2)
void flash_kernel(const bf16* __restrict__ qh, const bf16* __restrict__ ql,
                  const bf16* __restrict__ khf, const bf16* __restrict__ klf,
                  const bf16* __restrict__ vtf,
                  bf16*  __restrict__ opart,   // [SPLIT][N][D_H] unnormalized
                  float* __restrict__ mpart,   // [SPLIT][N] (exp2 domain)
                  float* __restrict__ lpart)   // [SPLIT][N]
{
    __shared__ bf16 k_s[2][16384];   // [buf][ kh: 0..8191 | kl: 8192..16383 ]

    const int t     = threadIdx.x;
    const int lane  = t & 63;
    const int wid   = t >> 6;
    const int lid   = lane & 15;
    const int quad  = lane >> 4;
    const int q0    = blockIdx.x * BQ;
    const int strip = wid * 32;               // 32 q-rows per wave
    const int sp    = blockIdx.y;
    const int tile0 = sp * (N_TOK / BKEY / SPLIT);
    const int tile1 = tile0 + (N_TOK / BKEY / SPLIT);

    // Q as B-operand of Q^T: resident for the whole kernel.
    bf16x8 b_hi[2][4], b_lo[2][4];            // [ct: qrow-tile][kc]
    #pragma unroll
    for (int ct = 0; ct < 2; ++ct) {
        const size_t rowb = (size_t)(q0 + strip + ct * 16 + lid) * D_H + quad * 8;
        #pragma unroll
        for (int kc = 0; kc < 4; ++kc) {
            b_hi[ct][kc] = *(const bf16x8*)(qh + rowb + kc * 32);
            b_lo[ct][kc] = *(const bf16x8*)(ql + rowb + kc * 32);
        }
    }

    bf16x8 vones;
    #pragma unroll
    for (int j = 0; j < 8; ++j) vones[j] = (bf16)1.0f;

    float m_run[2] = { -INFINITY, -INFINITY };   // per qrow-tile ct
    floatx4 l_acc[2];
    #pragma unroll
    for (int ct = 0; ct < 2; ++ct)
        #pragma unroll
        for (int r = 0; r < 4; ++r) l_acc[ct][r] = 0.f;
    floatx4 o_acc[8][2];                          // [dt][ct] = O^T frags
    #pragma unroll
    for (int dt = 0; dt < 8; ++dt)
        #pragma unroll
        for (int ct = 0; ct < 2; ++ct)
            #pragma unroll
            for (int r = 0; r < 4; ++r) o_acc[dt][ct][r] = 0.f;

    auto stage = [&](int tile, int buf) {
        const bf16* gh = khf + ((size_t)tile << 13) + (wid << 11) + (lane << 3);
        const bf16* gl = klf + ((size_t)tile << 13) + (wid << 11) + (lane << 3);
        bf16* lh = &k_s[buf][wid << 11];
        bf16* ll = lh + 8192;
        #pragma unroll
        for (int i = 0; i < 4; ++i) {
            __builtin_amdgcn_global_load_lds(
                (const __attribute__((address_space(1))) void*)(gh + i * 512),
                (__attribute__((address_space(3))) void*)(lh + i * 512), 16, 0, 0);
            __builtin_amdgcn_global_load_lds(
                (const __attribute__((address_space(1))) void*)(gl + i * 512),
                (__attribute__((address_space(3))) void*)(ll + i * 512), 16, 0, 0);
        }
    };

    stage(tile0, 0);

    for (int tt = tile0; tt < tile1; ++tt) {
        const int cb = (tt - tile0) & 1;
        __syncthreads();                      // buf cb staged; other buf free
        if (tt + 1 < tile1) stage(tt + 1, cb ^ 1);   // overlaps whole tile

        // ---- S^T = K . Q^T : split-bf16 3-pass, 96 MFMA ----
        const bf16* khp = &k_s[cb][0];
        const bf16* klp = &k_s[cb][8192];
        floatx4 s[4][2];                       // [mt: key-tile][ct: qrow-tile]
        #pragma unroll
        for (int mt = 0; mt < 4; ++mt)
            #pragma unroll
            for (int ct = 0; ct < 2; ++ct)
                #pragma unroll
                for (int r = 0; r < 4; ++r) s[mt][ct][r] = 0.f;

        // K-hi kc-level double buffer: prefetch kc+1 under kc's MFMAs.
        bf16x8 kh[2][4];                       // [kc&1][mt]
        #pragma unroll
        for (int mt = 0; mt < 4; ++mt)
            kh[0][mt] = *(const bf16x8*)&khp[(mt << 9) + (lane << 3)];

        __builtin_amdgcn_s_setprio(1);
        #pragma unroll
        for (int kc = 0; kc < 4; ++kc) {
            const int cur = kc & 1;
            if (kc < 3) {
                #pragma unroll
                for (int mt = 0; mt < 4; ++mt)
                    kh[cur ^ 1][mt] = *(const bf16x8*)
                        &khp[(((kc + 1) * 4 + mt) << 9) + (lane << 3)];
            }
            #pragma unroll
            for (int mt = 0; mt < 4; ++mt) {
                const int fo = ((kc * 4 + mt) << 9) + (lane << 3);
                bf16x8 al = *(const bf16x8*)&klp[fo];
                #pragma unroll
                for (int ct = 0; ct < 2; ++ct) {
                    s[mt][ct] = MFMA16(kh[cur][mt], b_hi[ct][kc], s[mt][ct]);
                    s[mt][ct] = MFMA16(al,          b_hi[ct][kc], s[mt][ct]);
                    s[mt][ct] = MFMA16(kh[cur][mt], b_lo[ct][kc], s[mt][ct]);
                }
            }
        }
        __builtin_amdgcn_s_setprio(0);

        // ---- prefetch V kc2=0 A-frags (consumed after softmax) ----
        const bf16* vb = vtf + ((size_t)tt << 13) + (lane << 3);
        bf16x8 vf0[8];
        #pragma unroll
        for (int dt = 0; dt < 8; ++dt)
            vf0[dt] = *(const bf16x8*)(vb + ((size_t)dt << 10));

        // ---- softmax (exp2 domain): balanced max tree + 2 shfl ----
        float mx[2];
        #pragma unroll
        for (int ct = 0; ct < 2; ++ct) {
            float a0 = fmaxf(s[0][ct][0], s[0][ct][1]);
            float a1 = fmaxf(s[0][ct][2], s[0][ct][3]);
            float a2 = fmaxf(s[1][ct][0], s[1][ct][1]);
            float a3 = fmaxf(s[1][ct][2], s[1][ct][3]);
            float a4 = fmaxf(s[2][ct][0], s[2][ct][1]);
            float a5 = fmaxf(s[2][ct][2], s[2][ct][3]);
            float a6 = fmaxf(s[3][ct][0], s[3][ct][1]);
            float a7 = fmaxf(s[3][ct][2], s[3][ct][3]);
            float b0 = fmaxf(fmaxf(a0, a1), fmaxf(a2, a3));
            float b1 = fmaxf(fmaxf(a4, a5), fmaxf(a6, a7));
            float c0 = fmaxf(b0, b1);
            c0 = fmaxf(c0, __shfl_xor(c0, 16, 64));
            c0 = fmaxf(c0, __shfl_xor(c0, 32, 64));
            mx[ct] = c0;
        }

        // defer-max: move the running max (and rescale) only when it grew
        // by more than RESCALE_THR; otherwise P <= 2^THR, safe in fp32.
        const bool need = __any((mx[0] - m_run[0] > RESCALE_THR) ||
                                (mx[1] - m_run[1] > RESCALE_THR));
        float alpha[2] = { 1.f, 1.f };
        if (need) {
            #pragma unroll
            for (int ct = 0; ct < 2; ++ct) {
                float mn = fmaxf(m_run[ct], mx[ct]);
                alpha[ct] = exp2f(m_run[ct] - mn);
                m_run[ct] = mn;
            }
        }

        uint32_t u0[4][2], u1[4][2];
        #pragma unroll
        for (int ct = 0; ct < 2; ++ct)
            #pragma unroll
            for (int mt = 0; mt < 4; ++mt) {
                float p0 = exp2f(s[mt][ct][0] - m_run[ct]);
                float p1 = exp2f(s[mt][ct][1] - m_run[ct]);
                float p2 = exp2f(s[mt][ct][2] - m_run[ct]);
                float p3 = exp2f(s[mt][ct][3] - m_run[ct]);
                u0[mt][ct] = pack2(p0, p1);
                u1[mt][ct] = pack2(p2, p3);
            }

        // ---- build P^T B-frags in-register (lane permutation) ----
        // target lane (quad,lid), frag (kc2,ct), j=0..7 needs
        // P^T[key=kc2*32+quad*8+j][qrow=ct*16+lid]; source element lives in
        // lane (2*(quad&1) + (j>>2))*16+lid, s[kc2*2+(quad>>1)][ct] reg j&3.
        bf16x8 pB[2][2];
        {
            const int lsrc = ((quad & 1) << 5) + lid;
            const bool himt = (quad & 2) != 0;
            #pragma unroll
            for (int kc2 = 0; kc2 < 2; ++kc2)
                #pragma unroll
                for (int ct = 0; ct < 2; ++ct) {
                    const int mA = kc2 * 2, mB = kc2 * 2 + 1;
                    uint32_t w0a = __shfl((int)u0[mA][ct], lsrc, 64);
                    uint32_t w0b = __shfl((int)u0[mB][ct], lsrc, 64);
                    uint32_t w1a = __shfl((int)u1[mA][ct], lsrc, 64);
                    uint32_t w1b = __shfl((int)u1[mB][ct], lsrc, 64);
                    uint32_t w2a = __shfl((int)u0[mA][ct], lsrc + 16, 64);
                    uint32_t w2b = __shfl((int)u0[mB][ct], lsrc + 16, 64);
                    uint32_t w3a = __shfl((int)u1[mA][ct], lsrc + 16, 64);
                    uint32_t w3b = __shfl((int)u1[mB][ct], lsrc + 16, 64);
                    union { uint32_t w[4]; bf16x8 v; } z;
                    z.w[0] = himt ? w0b : w0a;
                    z.w[1] = himt ? w1b : w1a;
                    z.w[2] = himt ? w2b : w2a;
                    z.w[3] = himt ? w3b : w3a;
                    pB[kc2][ct] = z.v;
                }
        }

        // ---- prefetch V kc2=1 ----
        bf16x8 vf1[8];
        #pragma unroll
        for (int dt = 0; dt < 8; ++dt)
            vf1[dt] = *(const bf16x8*)(vb + ((size_t)dt << 10) + 512);

        // ---- rescale (only when the running max actually moved >THR) ----
        if (need) {
            #pragma unroll
            for (int ct = 0; ct < 2; ++ct) {
                #pragma unroll
                for (int r = 0; r < 4; ++r) l_acc[ct][r] *= alpha[ct];
                #pragma unroll
                for (int dt = 0; dt < 8; ++dt)
                    #pragma unroll
                    for (int r = 0; r < 4; ++r)
                        o_acc[dt][ct][r] *= alpha[ct];
            }
        }

        // ---- O^T += V^T P^T ; l += ones.P^T ----
        __builtin_amdgcn_s_setprio(1);
        #pragma unroll
        for (int ct = 0; ct < 2; ++ct) {
            l_acc[ct] = MFMA16(vones, pB[0][ct], l_acc[ct]);
            l_acc[ct] = MFMA16(vones, pB[1][ct], l_acc[ct]);
        }
        #pragma unroll
        for (int dt = 0; dt < 8; ++dt)
            #pragma unroll
            for (int ct = 0; ct < 2; ++ct) {
                o_acc[dt][ct] = MFMA16(vf0[dt], pB[0][ct], o_acc[dt][ct]);
                o_acc[dt][ct] = MFMA16(vf1[dt], pB[1][ct], o_acc[dt][ct]);
            }
        __builtin_amdgcn_s_setprio(0);
    }

    // ---- epilogue: O^T regs -> opart[qrow][d] (packed u32 stores) ----
    uint32_t* opw = (uint32_t*)(opart + (size_t)sp * N_TOK * D_H);
    #pragma unroll
    for (int dt = 0; dt < 8; ++dt)
        #pragma unroll
        for (int ct = 0; ct < 2; ++ct) {
            int qrow  = q0 + strip + ct * 16 + lid;
            int dbase = dt * 16 + quad * 4;
            opw[(qrow * D_H + dbase) >> 1]     = pack2(o_acc[dt][ct][0], o_acc[dt][ct][1]);
            opw[(qrow * D_H + dbase + 2) >> 1] = pack2(o_acc[dt][ct][2], o_acc[dt][ct][3]);
        }
    if (quad == 0) {
        #pragma unroll
        for (int ct = 0; ct < 2; ++ct) {
            int row = q0 + strip + ct * 16 + lid;
            mpart[(size_t)sp * N_TOK + row] = m_run[ct];
            lpart[(size_t)sp * N_TOK + row] = l_acc[ct][0];
        }
    }
}

// ---------------------------------------------------------------------------
// Kernel 3: merge the SPLIT partials (exp2 domain).
// ---------------------------------------------------------------------------
__global__ __launch_bounds__(256)
void combine_kernel(const bf16* __restrict__ opart,
                    const float* __restrict__ mpart,
                    const float* __restrict__ lpart,
                    float* __restrict__ out)
{
    const int t   = threadIdx.x;
    const int row = blockIdx.x * 16 + (t >> 4);
    const int c0  = (t & 15) * 8;

    float ms[SPLIT], ls[SPLIT];
    float mstar = -INFINITY;
    #pragma unroll
    for (int s = 0; s < SPLIT; ++s) {
        ms[s] = mpart[(size_t)s * N_TOK + row];
        ls[s] = lpart[(size_t)s * N_TOK + row];
        mstar = fmaxf(mstar, ms[s]);
    }
    float acc[8] = {};
    float L = 0.f;
    #pragma unroll
    for (int s = 0; s < SPLIT; ++s) {
        float w = exp2f(ms[s] - mstar);
        L += w * ls[s];
        bf16x8 o = *(const bf16x8*)&opart[((size_t)s * N_TOK + row) * D_H + c0];
        #pragma unroll
        for (int j = 0; j < 8; ++j)
            acc[j] += w * (float)o[j];
    }
    float inv = 1.f / L;
    float* dst = &out[(size_t)row * D_H + c0];
    *(float4*)(dst + 0) = make_float4(acc[0] * inv, acc[1] * inv,
                                      acc[2] * inv, acc[3] * inv);
    *(float4*)(dst + 4) = make_float4(acc[4] * inv, acc[5] * inv,
                                      acc[6] * inv, acc[7] * inv);
}

// ---------------------------------------------------------------------------
extern "C" void kernel_launch(void* const* d_in, const int* in_sizes, int n_in,
                              void* d_out, int out_size, void* d_ws, size_t ws_size,
                              hipStream_t stream) {
    const float* x  = (const float*)d_in[0];
    const float* Wq = (const float*)d_in[1];
    const float* Wk = (const float*)d_in[2];
    const float* Wv = (const float*)d_in[3];
    float* out = (float*)d_out;

    bf16* wsb = (bf16*)d_ws;
    const size_t SZ = (size_t)N_TOK * D_H;
    bf16* xhf = wsb;
    bf16* xlf = xhf + (size_t)X_OCT * 8;
    bf16* whf = xlf + (size_t)X_OCT * 8;
    bf16* wlf = whf + (size_t)W_OCT * 8;
    bf16* qh  = wlf + (size_t)W_OCT * 8;
    bf16* ql  = qh + SZ;
    bf16* khf = ql + SZ;
    bf16* klf = khf + SZ;
    bf16* vtf = klf + SZ;
    bf16* opart = vtf + SZ;
    float* mpart = (float*)(opart + (size_t)SPLIT * SZ);
    float* lpart = mpart + (size_t)SPLIT * N_TOK;

    convert_kernel<<<dim3((X_OCT + W_OCT) / 256), 256, 0, stream>>>(
        x, Wq, Wk, Wv, xhf, xlf, whf, wlf);
    qkv_kernel<<<dim3(N_TOK / 64, 3), 256, 0, stream>>>(
        xhf, xlf, whf, wlf, qh, ql, khf, klf, vtf);
    flash_kernel<<<dim3(N_TOK / BQ, SPLIT), 256, 0, stream>>>(
        qh, ql, khf, klf, vtf, opart, mpart, lpart);
    combine_kernel<<<dim3(N_TOK / 16), 256, 0, stream>>>(opart, mpart, lpart, out);
}